// Round 12
// baseline (406.991 us; speedup 1.0000x reference)
//
#include <hip/hip_runtime.h>

// 3x3 PCF soft-shadow — 3-pass, full-line stores, 2 rounds, 7 dispatches.
// vis[i] = (1/9) * sum_{ii,jj} sigmoid((zbuf[b, clip(y+ii), clip(x+jj)] - (depth_z[i]-BIAS)) * 1000)
//
// R11 (394 us) closed the accounting: random-line write amplification is gone;
// remaining kernel time ~210 us ~= streaming traffic (~550 MB) + 16 serialized
// dispatches. This round shrinks both:
//  - P1 blocks own 16384 px (srec 128 KB LDS): run padding inflation 46%->23%
//  - vis overwrites the record's depth word in place (slab line already dirty
//    in L2) -> no separate vis array -> per-batch ws 11.5 MB -> nb=4 fits the
//    proven >=50.3 MB workspace -> 2 rounds
//  - gcur memset ONCE for all batches (32 KB) -> 7 dispatches total
// Structure (unchanged from R11): P1 LDS-sort into (batch, 64x64 tile) bins,
// runs padded to 8 recs = 64 B, burst full-line writes, pidx coalesced into
// out. P2 stages 66x66 tile in LDS, 9 taps from LDS, vis in place. P3
// de-permutes coalesced (vis gather L3-resident). Overflow -> SENT -> exact
// recompute in P3.

#define SHARPNESS 1000.0f
#define BIAS 0.008f
#define S2LOG2E 1442.6950408889634f    // 1000 * log2(e)

#define S_IMG   2048
#define NBATCH  8
#define HWK     (1 << 20)
#define TSH     6                      // 64x64 tiles
#define TPS     32
#define BPB     (TPS * TPS)            // 1024 bins per batch
#define CAP     1408                   // padded mean ~1258, sigma ~37 -> +4s; SENT covers rest
#define RPT     6                      // ceil(CAP / 256)
#define STW     66                     // staged tile width (64 + halo)
#define PXB     16384                  // pixels per P1 block
#define P1T     1024
#define PPT     (PXB / P1T)            // 16 px/thread
#define BLKB    (HWK / PXB)            // 64 P1 blocks per batch
#define SENT    0xFFFFFFFFu

typedef int      i4v __attribute__((ext_vector_type(4)));
typedef float    f2v __attribute__((ext_vector_type(2)));
typedef float    f4v __attribute__((ext_vector_type(4)));
typedef unsigned u2v __attribute__((ext_vector_type(2)));
typedef unsigned u4v __attribute__((ext_vector_type(4)));

__device__ __forceinline__ float sigf(float bb, float a) {
    const float t = (a - bb) * S2LOG2E;            // keep 2-op form: bit-stable
    return __builtin_amdgcn_rcpf(1.0f + exp2f(t));
}

// ---------------- Pass 1: LDS-sorted binning, burst full-line writes ----------------
__global__ __launch_bounds__(P1T, 1) void p1_bin(
    const int* __restrict__ xy_raw, const float* __restrict__ depth,
    u2v* __restrict__ slab, float* __restrict__ out /* pidx dest */,
    unsigned* __restrict__ gcur, int b0)
{
    __shared__ u2v      srec[PXB];     // 128 KB bin-sorted records
    __shared__ unsigned scn[BPB];      // hist -> inclusive scan -> cursor
    __shared__ unsigned lbase[BPB];    // exclusive local prefix
    __shared__ unsigned gbse[BPB];     // global run base (padded alloc)

    const int blk = blockIdx.x;
    const int bl  = blk >> 6;          // round-local batch (BLKB=64 blocks each)
    const int sub = blk & (BLKB - 1);
    const int tid = threadIdx.x;
    scn[tid] = 0;
    __syncthreads();

    const size_t pb_g = (size_t)(b0 + bl) * HWK + (size_t)sub * PXB;
    const i4v* xq = (const i4v*)xy_raw + pb_g / 2;     // 2 px per 16B
    const f2v* dq = (const f2v*)depth  + pb_g / 2;     // 2 px per 8B

    unsigned pk[PPT]; float dd[PPT];
#pragma unroll
    for (int j = 0; j < PPT / 2; ++j) {
        const i4v q = __builtin_nontemporal_load(&xq[j * P1T + tid]);
        const f2v d = __builtin_nontemporal_load(&dq[j * P1T + tid]);
        pk[2 * j]     = (unsigned)q.x | ((unsigned)q.y << 11);
        pk[2 * j + 1] = (unsigned)q.z | ((unsigned)q.w << 11);
        dd[2 * j] = d.x; dd[2 * j + 1] = d.y;
        atomicAdd(&scn[((q.y >> TSH) << 5) | (q.x >> TSH)], 1u);
        atomicAdd(&scn[((q.w >> TSH) << 5) | (q.z >> TSH)], 1u);
    }
    __syncthreads();

    const unsigned creg = scn[tid];    // my bin's count
    // Hillis-Steele inclusive scan over 1024 bins (in place)
    for (int ofs = 1; ofs < BPB; ofs <<= 1) {
        const unsigned u = (tid >= ofs) ? scn[tid - ofs] : 0u;
        __syncthreads();
        scn[tid] += u;
        __syncthreads();
    }
    const unsigned lb = scn[tid] - creg;
    lbase[tid] = lb;
    gbse[tid]  = atomicAdd(&gcur[(b0 + bl) * BPB + tid], (creg + 7u) & ~7u);
    scn[tid]   = lb;                   // becomes the scatter cursor
    __syncthreads();

    // scatter into LDS (bin-sorted); emit pidx coalesced into out
    u2v* px2 = (u2v*)(out + pb_g);
#pragma unroll
    for (int j = 0; j < PPT / 2; ++j) {
        u2v pi;
#pragma unroll
        for (int e = 0; e < 2; ++e) {
            const unsigned w = pk[2 * j + e];
            const int x = (int)(w & 0x7FFu), y = (int)(w >> 11);
            const int bn = ((y >> TSH) << 5) | (x >> TSH);
            const unsigned r = atomicAdd(&scn[bn], 1u);
            u2v rec;
            rec.x = (unsigned)(x & 63) | ((unsigned)(y & 63) << 6);
            rec.y = __float_as_uint(dd[2 * j + e]);
            srec[r] = rec;
            const unsigned pos = gbse[bn] + (r - lbase[bn]);
            const unsigned slot = (pos < CAP)
                ? (unsigned)(bl * BPB + bn) * CAP + pos : SENT;
            if (e == 0) pi.x = slot; else pi.y = slot;
        }
        px2[j * P1T + tid] = pi;
    }
    __syncthreads();

    // burst-write runs: wave w -> 64 bins; 64B-aligned, fully written
    const int wid = tid >> 6, lane = tid & 63;
    u2v* slb = slab + (size_t)bl * BPB * CAP;
    for (int bn = wid * 64; bn < wid * 64 + 64; ++bn) {
        const int c   = (int)(scn[bn] - lbase[bn]);
        const int len = (c + 7) & ~7;
        const int src = (int)lbase[bn];
        const int gp  = (int)gbse[bn];
        u2v* dst = slb + (size_t)bn * CAP;
        for (int k = lane; k < len; k += 64) {
            const int pos = gp + k;
            if (pos < CAP) {
                u2v r;
                if (k < c) r = srec[src + k];
                else { r.x = 0u; r.y = 0x7F800000u; }  // +inf depth -> vis 0
                dst[pos] = r;
            }
        }
    }
}

// ---------------- Pass 2: LDS tile, vis in place over depth word ----------------
__global__ __launch_bounds__(256, 8) void p2_tile(
    const float* __restrict__ zbuf, u2v* __restrict__ slab,
    const unsigned* __restrict__ gcur, int b0)
{
    __shared__ float zt[STW * STW];                // 17.4 KB -> 8 blocks/CU
    const int gb  = blockIdx.x;                    // round-local bin
    const int tid = threadIdx.x;
    const int bl  = gb >> 10;
    const int t   = gb & (BPB - 1);
    const int tx  = t & 31, ty = t >> 5;
    const float* zb = zbuf + (size_t)(b0 + bl) * ((size_t)S_IMG * S_IMG);
    const int x0 = tx * 64 - 1, y0 = ty * 64 - 1;

    const int n   = min((int)gcur[(b0 + bl) * BPB + t], CAP);
    const int nc  = n - 1;
    const int ncc = max(nc, 0);
    u2v* sl = slab + (size_t)gb * CAP;

    u2v Rc[RPT];                                   // preload records early
#pragma unroll
    for (int j = 0; j < RPT; ++j)
        Rc[j] = sl[min(j * 256 + tid, ncc)];

    for (int i = tid; i < STW * STW; i += 256) {
        const int r  = i / STW, c = i - r * STW;
        const int gy = min(max(y0 + r, 0), S_IMG - 1);
        const int gx = min(max(x0 + c, 0), S_IMG - 1);
        zt[i] = zb[(size_t)gy * S_IMG + gx];       // zbuf read ONCE, coalesced
    }
    __syncthreads();

    float* slf = (float*)sl;
#pragma unroll
    for (int j = 0; j < RPT; ++j) {
        const unsigned w = Rc[j].x;
        const float a  = __uint_as_float(Rc[j].y) - BIAS;
        const float* p = zt + (int)((w >> 6) & 63u) * STW + (int)(w & 63u);
        const float v =
              sigf(p[0],           a) + sigf(p[1],           a) + sigf(p[2],           a)
            + sigf(p[STW],         a) + sigf(p[STW + 1],     a) + sigf(p[STW + 2],     a)
            + sigf(p[2 * STW],     a) + sigf(p[2 * STW + 1], a) + sigf(p[2 * STW + 2], a);
        const int k = j * 256 + tid;
        if (k <= nc) slf[2 * k + 1] = v * (1.0f / 9.0f);  // line already dirty in L2
    }
}

// ---------------- Pass 3: pidx from out -> gather vis -> overwrite out ----------------
__global__ __launch_bounds__(256) void p3_out(
    const float* __restrict__ slabf, float* __restrict__ out,
    const float* __restrict__ zbuf, const float* __restrict__ depth,
    const int* __restrict__ xy_raw, int b0)
{
    const int tid = threadIdx.x;
    const size_t pxbase = (size_t)b0 * HWK + (size_t)blockIdx.x * 4096;
    const u4v* px4 = (const u4v*)(out + pxbase);

    u4v P[4];
#pragma unroll
    for (int j = 0; j < 4; ++j)
        P[j] = px4[j * 256 + tid];                 // pidx (written by P1)

    f4v V[4];
#pragma unroll
    for (int j = 0; j < 4; ++j) {
#pragma unroll
        for (int e = 0; e < 4; ++e) {
            const unsigned pi = P[j][e];
            float v;
            if (pi != SENT) {
                v = slabf[2 * (size_t)pi + 1];     // L3-resident vis (in-place)
            } else {                               // overflow: recompute (rare)
                const size_t il = pxbase + (size_t)(j * 256 + tid) * 4 + e;
                const int batch = (int)(il >> 20);
                const float a = depth[il] - BIAS;
                const int x = xy_raw[2 * il], y = xy_raw[2 * il + 1];
                const float* zbb = zbuf + (size_t)batch * ((size_t)S_IMG * S_IMG);
                float vv = 0.0f;
                for (int ii = -1; ii <= 1; ++ii) {
                    const int yi = min(max(y + ii, 0), S_IMG - 1);
                    const float* row = zbb + (size_t)yi * S_IMG;
                    for (int jj = -1; jj <= 1; ++jj)
                        vv += sigf(row[min(max(x + jj, 0), S_IMG - 1)], a);
                }
                v = vv * (1.0f / 9.0f);
            }
            V[j][e] = v;
        }
    }

    f4v* o4 = (f4v*)(out + pxbase);                // same thread, same addrs
#pragma unroll
    for (int j = 0; j < 4; ++j)
        __builtin_nontemporal_store(V[j], &o4[j * 256 + tid]);
}

// ---------------- fallback: direct kernel ----------------
__global__ __launch_bounds__(256) void pcf_shadow_generic(
    const float* __restrict__ zbuf, const float* __restrict__ depth_z,
    const int2* __restrict__ xy, const int* __restrict__ image_size_p,
    float* __restrict__ out, int total, int zbuf_elems)
{
    const int i = blockIdx.x * blockDim.x + threadIdx.x;
    if (i >= total) return;
    const int S  = *image_size_p;
    const int SS = S * S;
    const int N  = zbuf_elems / SS;
    const int hwk = total / N;
    const int b   = i / hwk;
    const float a = depth_z[i] - BIAS;
    const int2 p  = xy[i];
    const float* base = zbuf + (size_t)b * (size_t)SS;
    float vis = 0.0f;
#pragma unroll
    for (int ii = -1; ii <= 1; ++ii) {
        const int yi = min(max(p.y + ii, 0), S - 1);
        const float* row = base + (size_t)yi * (size_t)S;
#pragma unroll
        for (int jj = -1; jj <= 1; ++jj) {
            const int xi = min(max(p.x + jj, 0), S - 1);
            vis += 1.0f / (1.0f + __expf((a - row[xi]) * SHARPNESS));
        }
    }
    out[i] = vis * (1.0f / 9.0f);
}

extern "C" void kernel_launch(void* const* d_in, const int* in_sizes, int n_in,
                              void* d_out, int out_size, void* d_ws, size_t ws_size,
                              hipStream_t stream) {
    const float* zbuf     = (const float*)d_in[0];
    const float* depth_z  = (const float*)d_in[1];
    const int*   xy_raw   = (const int*)d_in[2];
    const int*   img_size = (const int*)d_in[3];
    float*       out      = (float*)d_out;

    const int zbuf_elems = in_sizes[0];   // N*S*S
    const int total      = in_sizes[1];   // N*H*W*K

    if (zbuf_elems == NBATCH * S_IMG * S_IMG && total == NBATCH * HWK) {
        const size_t slab_pb = (size_t)BPB * CAP * 8ull;       // 11.53 MB
        const size_t gcur_b  = (size_t)NBATCH * BPB * 4ull;    // 32 KB
        int nb = 0;
        if      (ws_size >= 8 * slab_pb + gcur_b) nb = 8;      // 92.3 MB
        else if (ws_size >= 4 * slab_pb + gcur_b) nb = 4;      // 46.2 MB <= proven 50.3
        else if (ws_size >= 2 * slab_pb + gcur_b) nb = 2;
        else if (ws_size >= 1 * slab_pb + gcur_b) nb = 1;

        if (nb) {
            u2v*      slab = (u2v*)d_ws;
            unsigned* gcur = (unsigned*)((char*)d_ws + (size_t)nb * slab_pb);
            hipMemsetAsync(gcur, 0, gcur_b, stream);           // once, all batches
            for (int b0 = 0; b0 < NBATCH; b0 += nb) {
                p1_bin <<<nb * BLKB, P1T, 0, stream>>>(xy_raw, depth_z, slab, out, gcur, b0);
                p2_tile<<<nb * BPB,  256, 0, stream>>>(zbuf, slab, gcur, b0);
                p3_out <<<nb * 256,  256, 0, stream>>>((const float*)slab, out,
                                                       zbuf, depth_z, xy_raw, b0);
            }
            return;
        }
    }
    const int block = 256;
    const int grid  = (total + block - 1) / block;
    pcf_shadow_generic<<<grid, block, 0, stream>>>(zbuf, depth_z, (const int2*)xy_raw,
                                                   img_size, out, total, zbuf_elems);
}